// Round 4
// baseline (1279.858 us; speedup 1.0000x reference)
//
#include <hip/hip_runtime.h>

// ---------------------------------------------------------------------------
// update_v (PDN-GNN) on MI355X / gfx950.  All float I/O fp32.
//
// R4 changes vs R3 (passed, 1235 us, absmax 3.66e-4):
//  - Activations carried as bf16 (hi,lo) PLANES between layers; the fp32->
//    bf16 split happens once in each producer epilogue, not per GEMM K-tile.
//  - k_gemm: m97-style staging — __builtin_amdgcn_global_load_lds width=16
//    into packed [128][32] u16 LDS tiles (Ah/Al/Bh/Bl, 32 KB), zero staging
//    VALU, no register round-trip. 3-term MFMA (AhWh+AlWh+AhWl) unchanged.
//  - Flat workspace (~223 MB, no aliasing): harness poison shows ws ~1.23 GB.
//
// Workspace layout (bytes):
//   edgep  0            12,800,000
//   ew     12,800,000    6,400,000
//   midx   19,200,000    2,400,000
//   cntC   21,600,000      200,000 \
//   cntM   21,800,000      200,000  } memset together
//   deg    22,000,000      200,000 /
//   offC   22,200,000      200,004
//   curC   22,400,256      200,000
//   offM   22,600,256      200,004
//   curM   22,800,512      200,000
//   dinv   23,000,512      200,000
//   Wh     23,200,512      532,480
//   Wl     23,732,992      532,480
//   partC  24,265,472          784
//   partM  24,266,368          784
//   XcatH  24,268,800   16,000,000   (50000 x 160 u16)
//   XcatL  40,268,800   16,000,000
//   v1h    56,268,800   12,800,000   (50000 x 128 u16)
//   v1l    69,068,800   12,800,000
//   xw     81,868,800   12,800,000   (single bf16 plane, gather input)
//   gh     94,668,800   12,800,000
//   gl    107,468,800   12,800,000
//   s0h   120,268,800   25,600,000   (50000 x 256 u16)
//   s0l   145,868,800   25,600,000
//   s1h   171,468,800   25,600,000
//   s1l   197,068,800   25,600,000
//   total 222,668,800
// ---------------------------------------------------------------------------

#define Nn 50000
#define Mm 600000
#define Ee 1600000
#define NB 196          // ceil(Nn/256)

typedef unsigned short u16;
typedef unsigned int u32;
typedef __attribute__((ext_vector_type(8))) short bh8;   // 8 bf16 = 4 VGPRs
typedef __attribute__((ext_vector_type(4))) float f4;    // 4 fp32 acc

__device__ __forceinline__ float bf2f(u16 u) {
    union { u32 i; float f; } v; v.i = ((u32)u) << 16; return v.f;
}
__device__ __forceinline__ u16 f2bf(float f) {   // RNE, finite inputs
    union { float f; u32 u; } v; v.f = f;
    return (u16)((v.u + 0x7fffu + ((v.u >> 16) & 1u)) >> 16);
}

// global -> LDS direct copy, 16 B per lane (m97 pattern, width=16)
#define GLD16(gp, lp)                                                         \
    __builtin_amdgcn_global_load_lds(                                         \
        (const __attribute__((address_space(1))) unsigned int*)(gp),          \
        (__attribute__((address_space(3))) unsigned int*)(lp), 16, 0, 0)

// --------------------------- edge MLP + degree -----------------------------
__global__ __launch_bounds__(256) void k_edge(
    const float* __restrict__ attr, const int* __restrict__ eidx,
    const float* __restrict__ w1, const float* __restrict__ b1,
    const float* __restrict__ w2, const float* __restrict__ b2,
    float* __restrict__ ew, float* __restrict__ deg, int* __restrict__ cntC)
{
    __shared__ float sW1[64], sB1[8], sW2[8], sB2;
    int t = threadIdx.x;
    if (t < 64) sW1[t] = w1[t];
    if (t < 8) { sB1[t] = b1[t]; sW2[t] = w2[t]; }
    if (t == 0) sB2 = b2[0];
    __syncthreads();
    int e = blockIdx.x * 256 + t;
    if (e >= Ee) return;
    float4 q0 = *(const float4*)(attr + (size_t)e * 8);
    float4 q1 = *(const float4*)(attr + (size_t)e * 8 + 4);
    float a[8] = { q0.x, q0.y, q0.z, q0.w, q1.x, q1.y, q1.z, q1.w };
    float z = sB2;
#pragma unroll
    for (int j = 0; j < 8; ++j) {
        float h = sB1[j];
#pragma unroll
        for (int k = 0; k < 8; ++k) h += a[k] * sW1[j * 8 + k];
        z += fmaxf(h, 0.f) * sW2[j];
    }
    float s = 1.f / (1.f + __expf(-z));
    ew[e] = s;
    int c = eidx[Ee + e];
    atomicAdd(&deg[c], s);
    atomicAdd(&cntC[c], 1);
}

__global__ __launch_bounds__(256) void k_cntm(const int* __restrict__ ii,
                                              int* __restrict__ cnt)
{
    int m = blockIdx.x * 256 + threadIdx.x;
    if (m < Mm) atomicAdd(&cnt[ii[m]], 1);
}

// --------------------- 3-phase multi-block exclusive scan ------------------
__global__ __launch_bounds__(256) void k_scanA(
    const int* __restrict__ cnt, int* __restrict__ loc, int* __restrict__ part)
{
    __shared__ int buf[256];
    int t = threadIdx.x, i = blockIdx.x * 256 + t;
    int v = (i < Nn) ? cnt[i] : 0;
    buf[t] = v;
    __syncthreads();
#pragma unroll
    for (int d = 1; d < 256; d <<= 1) {
        int x = (t >= d) ? buf[t - d] : 0;
        __syncthreads();
        buf[t] += x;
        __syncthreads();
    }
    if (i < Nn) loc[i] = buf[t] - v;        // local exclusive
    if (t == 255) part[blockIdx.x] = buf[255];
}

__global__ __launch_bounds__(256) void k_scanB(int* __restrict__ pA,
                                               int* __restrict__ pB)
{
    int* p = blockIdx.x ? pB : pA;
    __shared__ int buf[256];
    int t = threadIdx.x;
    int v = (t < NB) ? p[t] : 0;
    buf[t] = v;
    __syncthreads();
#pragma unroll
    for (int d = 1; d < 256; d <<= 1) {
        int x = (t >= d) ? buf[t - d] : 0;
        __syncthreads();
        buf[t] += x;
        __syncthreads();
    }
    if (t < NB) p[t] = buf[t] - v;
}

__global__ __launch_bounds__(256) void k_scanC(
    const int* __restrict__ cnt, const int* __restrict__ part,
    int* __restrict__ off, int* __restrict__ cur,
    const float* __restrict__ deg, float* __restrict__ dinv)
{
    int t = threadIdx.x, i = blockIdx.x * 256 + t;
    if (i >= Nn) return;
    int v = off[i] + part[blockIdx.x];
    off[i] = v;
    cur[i] = v;
    if (i == Nn - 1) off[Nn] = v + cnt[i];
    if (dinv) {
        float d = deg[i];
        dinv[i] = (d > 0.f) ? rsqrtf(fmaxf(d, 1e-30f)) : 0.f;
    }
}

// --------------------------- CSR scatter -----------------------------------
__global__ __launch_bounds__(256) void k_scatter_col(
    const int* __restrict__ eidx, const float* __restrict__ ew,
    const float* __restrict__ dinv, int* __restrict__ cur,
    int2* __restrict__ edgep)
{
    int e = blockIdx.x * 256 + threadIdx.x;
    if (e >= Ee) return;
    int r = eidx[e], c = eidx[Ee + e];
    float nm = dinv[r] * ew[e] * dinv[c];
    int idx = atomicAdd(&cur[c], 1);       // cur starts at offC -> absolute
    edgep[idx] = make_int2(r, __float_as_int(nm));
}

__global__ __launch_bounds__(256) void k_scatter_m(
    const int* __restrict__ ii, int* __restrict__ cur, int* __restrict__ midx)
{
    int m = blockIdx.x * 256 + threadIdx.x;
    if (m >= Mm) return;
    midx[atomicAdd(&cur[ii[m]], 1)] = m;
}

// --------------------------- e2 segment sum -> Xcat hi/lo planes -----------
__global__ __launch_bounds__(256) void k_segsum(
    const int* __restrict__ offM, const int* __restrict__ midx,
    const float* __restrict__ e2, const float* __restrict__ afe,
    u16* __restrict__ XH, u16* __restrict__ XL)
{
    int wv = threadIdx.x >> 6, lane = threadIdx.x & 63;
    int n = blockIdx.x * 4 + wv;
    if (n >= Nn) return;
    int j0 = offM[n], j1 = offM[n + 1];
    float a0 = 0.f, a1 = 0.f;
    int j = j0;
    if (j < j1) {
        int m = midx[j];
        float2 p = *(const float2*)(e2 + (size_t)m * 128 + lane * 2);
        for (++j; j < j1; ++j) {
            int m2 = midx[j];
            float2 p2 = *(const float2*)(e2 + (size_t)m2 * 128 + lane * 2);
            a0 += p.x; a1 += p.y;
            p = p2;
        }
        a0 += p.x; a1 += p.y;
    }
    u16 h0 = f2bf(a0), h1 = f2bf(a1);
    u16 l0 = f2bf(a0 - bf2f(h0)), l1 = f2bf(a1 - bf2f(h1));
    *(u32*)&XH[(size_t)n * 160 + lane * 2] = (u32)h0 | ((u32)h1 << 16);
    *(u32*)&XL[(size_t)n * 160 + lane * 2] = (u32)l0 | ((u32)l1 << 16);
    if (lane < 32) {                       // channels 128..159: afe then pad 0
        int ch = 128 + lane;
        float v = (ch < 135) ? afe[(size_t)n * 7 + (ch - 128)] : 0.f;
        u16 h = f2bf(v);
        XH[(size_t)n * 160 + ch] = h;
        XL[(size_t)n * 160 + ch] = f2bf(v - bf2f(h));
    }
}

// --------------------------- weight split (fp32 -> bf16 hi+lo) -------------
__global__ __launch_bounds__(256) void k_splitw(
    const float* __restrict__ src, u16* __restrict__ h, u16* __restrict__ l,
    int rows, int sc, int dc)
{
    int idx = blockIdx.x * 256 + threadIdx.x;
    if (idx >= rows * dc) return;
    int r = idx / dc, c = idx % dc;
    float x = (c < sc) ? src[(size_t)r * sc + c] : 0.f;
    u16 hh = f2bf(x);
    h[idx] = hh;
    l[idx] = f2bf(x - bf2f(hh));
}

// --------------------------- split MFMA GEMM -------------------------------
// Y = op(X @ W^T + bias); X,W given as bf16 hi/lo planes [rows][K] u16.
// acc += Ah*Wh + Al*Wh + Ah*Wl (~fp32, err ~2^-17).
// Tile 128x128, BK=32, 4 waves (2x2 of 64x64), 16x16x32 MFMA.
// Staging: global_load_lds width=16 into packed [128][32] u16 planes; wave wv
// stages plane wv (8 x 1KB issues; lane l -> row 16i+(l>>2), chunk l&3).
// Layouts (m89/m91): A lane holds A[m=lane&15][k=(lane>>4)*8+j]; B likewise;
// D: col=lane&15, row=(lane>>4)*4+r.  flags: 1=relu, 2=single-bf16 out (Yh).
__global__ __launch_bounds__(256) void k_gemm(
    const u16* __restrict__ Ah, const u16* __restrict__ Al,
    const u16* __restrict__ Bh, const u16* __restrict__ Bl,
    const float* __restrict__ bias, u16* __restrict__ Yh, u16* __restrict__ Yl,
    int M, int K, int NO, int flags)
{
    __shared__ __align__(16) u16 sT[4][128 * 32];   // Ah, Al, Bh, Bl: 32 KB
    const int t = threadIdx.x;
    const int m0 = blockIdx.x * 128, n0 = blockIdx.y * 128;
    const int lane = t & 63, wv = t >> 6;
    const int wm = (wv >> 1) * 64, wn = (wv & 1) * 64;
    const int lr = lane & 15, lq = lane >> 4;
    // staging role for this wave
    const u16* gplane = (wv == 0) ? Ah : (wv == 1) ? Al : (wv == 2) ? Bh : Bl;
    u16* lplane = &sT[wv][0];
    const int rbase = (wv < 2) ? m0 : n0;
    const int rlim = (wv < 2) ? (M - 1) : 0x7fffffff;
    const int srow = lane >> 2;            // 0..15 within 16-row group
    const int scol = (lane & 3) * 8;       // u16 chunk offset
    f4 acc[4][4] = {};

    for (int k0 = 0; k0 < K; k0 += 32) {
        __syncthreads();                   // prev frag reads done
#pragma unroll
        for (int i = 0; i < 8; ++i) {
            int grow = rbase + i * 16 + srow;
            if (grow > rlim) grow = rlim;  // clamp (dup rows, discarded)
            const u16* gp = gplane + (size_t)grow * K + k0 + scol;
            GLD16(gp, lplane + i * 512);
        }
        __syncthreads();                   // vmcnt(0) drains the LDS-DMA
        bh8 fah[4], fal[4], fbh[4], fbl[4];
#pragma unroll
        for (int i = 0; i < 4; ++i) {
            fah[i] = *(const bh8*)&sT[0][(wm + i * 16 + lr) * 32 + lq * 8];
            fal[i] = *(const bh8*)&sT[1][(wm + i * 16 + lr) * 32 + lq * 8];
            fbh[i] = *(const bh8*)&sT[2][(wn + i * 16 + lr) * 32 + lq * 8];
            fbl[i] = *(const bh8*)&sT[3][(wn + i * 16 + lr) * 32 + lq * 8];
        }
#pragma unroll
        for (int mi = 0; mi < 4; ++mi)
#pragma unroll
            for (int ni = 0; ni < 4; ++ni) {
                acc[mi][ni] = __builtin_amdgcn_mfma_f32_16x16x32_bf16(
                    fah[mi], fbh[ni], acc[mi][ni], 0, 0, 0);
                acc[mi][ni] = __builtin_amdgcn_mfma_f32_16x16x32_bf16(
                    fal[mi], fbh[ni], acc[mi][ni], 0, 0, 0);
                acc[mi][ni] = __builtin_amdgcn_mfma_f32_16x16x32_bf16(
                    fah[mi], fbl[ni], acc[mi][ni], 0, 0, 0);
            }
    }
#pragma unroll
    for (int ni = 0; ni < 4; ++ni) {
        int gn = n0 + wn + ni * 16 + lr;
        float bv = bias ? bias[gn] : 0.f;
#pragma unroll
        for (int mi = 0; mi < 4; ++mi) {
#pragma unroll
            for (int r = 0; r < 4; ++r) {
                int gm = m0 + wm + mi * 16 + lq * 4 + r;
                if (gm < M) {
                    float v = acc[mi][ni][r] + bv;
                    if (flags & 1) v = fmaxf(v, 0.f);
                    u16 h = f2bf(v);
                    Yh[(size_t)gm * NO + gn] = h;
                    if (!(flags & 2))
                        Yl[(size_t)gm * NO + gn] = f2bf(v - bf2f(h));
                }
            }
        }
    }
}

// --------------------------- conv gather (CSR by col) ----------------------
// wave-per-node, depth-2 pipelined; xw single bf16 plane in, hi/lo planes out
__global__ __launch_bounds__(256) void k_gather(
    const int* __restrict__ off, const int2* __restrict__ edgep,
    const u16* __restrict__ xw, u16* __restrict__ OH, u16* __restrict__ OL,
    int relu)
{
    int wv = threadIdx.x >> 6, lane = threadIdx.x & 63;
    int n = blockIdx.x * 4 + wv;
    if (n >= Nn) return;
    int j0 = off[n], j1 = off[n + 1];
    float a0 = 0.f, a1 = 0.f;
    int j = j0;
    if (j < j1) {
        int2 ep = edgep[j];
        u32 p = *(const u32*)(xw + (size_t)ep.x * 128 + lane * 2);
        for (++j; j < j1; ++j) {
            int2 ep2 = edgep[j];
            u32 p2 = *(const u32*)(xw + (size_t)ep2.x * 128 + lane * 2);
            float w = __int_as_float(ep.y);
            a0 += w * bf2f((u16)(p & 0xffff));
            a1 += w * bf2f((u16)(p >> 16));
            ep = ep2; p = p2;
        }
        float w = __int_as_float(ep.y);
        a0 += w * bf2f((u16)(p & 0xffff));
        a1 += w * bf2f((u16)(p >> 16));
    }
    if (relu) { a0 = fmaxf(a0, 0.f); a1 = fmaxf(a1, 0.f); }
    u16 h0 = f2bf(a0), h1 = f2bf(a1);
    u16 l0 = f2bf(a0 - bf2f(h0)), l1 = f2bf(a1 - bf2f(h1));
    *(u32*)&OH[(size_t)n * 128 + lane * 2] = (u32)h0 | ((u32)h1 << 16);
    *(u32*)&OL[(size_t)n * 128 + lane * 2] = (u32)l0 | ((u32)l1 << 16);
}

// --------------------------- final 256 -> 1 --------------------------------
__global__ __launch_bounds__(256) void k_final(
    const u16* __restrict__ Sh, const u16* __restrict__ Sl,
    const float* __restrict__ lw, float* __restrict__ out)
{
    __shared__ float w[256];
    int t = threadIdx.x;
    w[t] = lw[t];
    __syncthreads();
    int n = blockIdx.x * 4 + (t >> 6);
    int lane = t & 63;
    if (n >= Nn) return;
    float s = 0.f;
#pragma unroll
    for (int g = 0; g < 2; ++g) {
        int c = g * 128 + lane * 2;
        u32 hh = *(const u32*)(Sh + (size_t)n * 256 + c);
        u32 ll = *(const u32*)(Sl + (size_t)n * 256 + c);
        float x0 = bf2f((u16)(hh & 0xffff)) + bf2f((u16)(ll & 0xffff));
        float x1 = bf2f((u16)(hh >> 16)) + bf2f((u16)(ll >> 16));
        s += x0 * w[c] + x1 * w[c + 1];
    }
#pragma unroll
    for (int d = 32; d >= 1; d >>= 1) s += __shfl_xor(s, d, 64);
    if (lane == 0) out[n] = s;
}

// ---------------------------------------------------------------------------
extern "C" void kernel_launch(void* const* d_in, const int* in_sizes, int n_in,
                              void* d_out, int out_size, void* d_ws, size_t ws_size,
                              hipStream_t stream)
{
    (void)in_sizes; (void)n_in; (void)out_size; (void)ws_size;
    const float* e2       = (const float*)d_in[0];
    const int*   iidx     = (const int*)d_in[1];
    const float* afe      = (const float*)d_in[2];
    const int*   bei      = (const int*)d_in[3];
    const float* battr    = (const float*)d_in[4];
    const float* lin_v_w  = (const float*)d_in[5];
    const float* lin_v_b  = (const float*)d_in[6];
    const float* conv_w   = (const float*)d_in[7];
    const float* w1       = (const float*)d_in[8];
    const float* b1       = (const float*)d_in[9];
    const float* w2       = (const float*)d_in[10];
    const float* b2       = (const float*)d_in[11];
    const float* lin_up_w = (const float*)d_in[12];
    const float* lin_up_b = (const float*)d_in[13];
    const float* lins_w   = (const float*)d_in[14];
    const float* lins_b   = (const float*)d_in[15];
    const float* lin_w    = (const float*)d_in[16];

    char* ws = (char*)d_ws;
    int2*  edgep = (int2*) (ws + 0);
    float* ew    = (float*)(ws + 12800000);
    int*   midx  = (int*)  (ws + 19200000);
    int*   cntC  = (int*)  (ws + 21600000);
    int*   cntM  = (int*)  (ws + 21800000);
    float* deg   = (float*)(ws + 22000000);
    int*   offC  = (int*)  (ws + 22200000);
    int*   curC  = (int*)  (ws + 22400256);
    int*   offM  = (int*)  (ws + 22600256);
    int*   curM  = (int*)  (ws + 22800512);
    float* dinv  = (float*)(ws + 23000512);
    u16*   Wh    = (u16*)  (ws + 23200512);     // 266,240 elements
    u16*   Wl    = (u16*)  (ws + 23732992);
    int*   partC = (int*)  (ws + 24265472);
    int*   partM = (int*)  (ws + 24266368);
    u16*   XcatH = (u16*)  (ws + 24268800);
    u16*   XcatL = (u16*)  (ws + 40268800);
    u16*   v1h   = (u16*)  (ws + 56268800);
    u16*   v1l   = (u16*)  (ws + 69068800);
    u16*   xw    = (u16*)  (ws + 81868800);
    u16*   gh    = (u16*)  (ws + 94668800);
    u16*   gl    = (u16*)  (ws + 107468800);
    u16*   s0h   = (u16*)  (ws + 120268800);
    u16*   s0l   = (u16*)  (ws + 145868800);
    u16*   s1h   = (u16*)  (ws + 171468800);
    u16*   s1l   = (u16*)  (ws + 197068800);

    // Wh/Wl element offsets per matrix:
    const int oWv = 0, oConv = 20480, oLup = 36864, oLins = 69632;

    hipMemsetAsync(ws + 21600000, 0, 3 * Nn * 4, stream);   // cntC,cntM,deg

    k_edge<<<(Ee + 255) / 256, 256, 0, stream>>>(battr, bei, w1, b1, w2, b2,
                                                 ew, deg, cntC);
    k_cntm<<<(Mm + 255) / 256, 256, 0, stream>>>(iidx, cntM);
    k_scanA<<<NB, 256, 0, stream>>>(cntC, offC, partC);
    k_scanA<<<NB, 256, 0, stream>>>(cntM, offM, partM);
    k_scanB<<<2, 256, 0, stream>>>(partC, partM);
    k_scanC<<<NB, 256, 0, stream>>>(cntC, partC, offC, curC, deg, dinv);
    k_scanC<<<NB, 256, 0, stream>>>(cntM, partM, offM, curM, nullptr, nullptr);
    k_scatter_col<<<(Ee + 255) / 256, 256, 0, stream>>>(bei, ew, dinv, curC,
                                                        edgep);
    k_scatter_m<<<(Mm + 255) / 256, 256, 0, stream>>>(iidx, curM, midx);
    k_segsum<<<(Nn + 3) / 4, 256, 0, stream>>>(offM, midx, e2, afe,
                                               XcatH, XcatL);

    k_splitw<<<(128 * 160 + 255) / 256, 256, 0, stream>>>(
        lin_v_w, Wh + oWv, Wl + oWv, 128, 135, 160);
    k_splitw<<<(128 * 128 + 255) / 256, 256, 0, stream>>>(
        conv_w, Wh + oConv, Wl + oConv, 128, 128, 128);
    k_splitw<<<(256 * 128 + 255) / 256, 256, 0, stream>>>(
        lin_up_w, Wh + oLup, Wl + oLup, 256, 128, 128);
    k_splitw<<<(768 * 256 + 255) / 256, 256, 0, stream>>>(
        lins_w, Wh + oLins, Wl + oLins, 768, 256, 256);

#define GEMM(XH, XL, WO, Bp, YH, YL, M_, K_, NO_, FL_)                        \
    k_gemm<<<dim3(((M_) + 127) / 128, (NO_) / 128), 256, 0, stream>>>(        \
        XH, XL, Wh + (WO), Wl + (WO), (const float*)(Bp), YH, YL,             \
        M_, K_, NO_, FL_)

    GEMM(XcatH, XcatL, oWv, lin_v_b, v1h, v1l, Nn, 160, 128, 0);
    GEMM(v1h, v1l, oConv, nullptr, xw, nullptr, Nn, 128, 128, 2);
    k_gather<<<(Nn + 3) / 4, 256, 0, stream>>>(offC, edgep, xw, gh, gl, 0);
    GEMM(gh, gl, oConv, nullptr, xw, nullptr, Nn, 128, 128, 2);
    k_gather<<<(Nn + 3) / 4, 256, 0, stream>>>(offC, edgep, xw, gh, gl, 1);
    GEMM(gh, gl, oLup, lin_up_b, s0h, s0l, Nn, 128, 256, 0);
    GEMM(s0h, s0l, oLins + 0 * 65536, lins_b + 0,   s1h, s1l, Nn, 256, 256, 1);
    GEMM(s1h, s1l, oLins + 1 * 65536, lins_b + 256, s0h, s0l, Nn, 256, 256, 1);
    GEMM(s0h, s0l, oLins + 2 * 65536, lins_b + 512, s1h, s1l, Nn, 256, 256, 1);
    k_final<<<(Nn + 3) / 4, 256, 0, stream>>>(s1h, s1l, lin_w, (float*)d_out);
#undef GEMM
}